// Round 4
// baseline (360.908 us; speedup 1.0000x reference)
//
#include <hip/hip_runtime.h>
#include <hip/hip_bf16.h>

#define NN 50000
#define NE 800000
#define FD 128
#define L1CAP 16000
#define E1CAP 131072
#define E2CAP 32768
#define L2CAP 512

// ---------------- frontier construction ----------------

__global__ void k_mark(const int* __restrict__ states, const int* __restrict__ actions,
                       int* __restrict__ flagL2, int* __restrict__ flagL1,
                       int* __restrict__ nodeL2, int* __restrict__ cnt) {
    int i = blockIdx.x * blockDim.x + threadIdx.x;
    if (i == 0) cnt[3] = 257;   // fixed layer-2 slot count
    if (i < 257) {
        int n = (i < 256) ? states[i] : actions[0];
        flagL2[n] = i + 1;      // duplicate states race: one slot wins; losing slots
        flagL1[n] = 1;          // are never read (readout maps through flagL2)
        nodeL2[i] = n;
    }
}

// Edge scan, 4 edges/thread, wave-aggregated compaction counter (one
// same-address atomic per wave instead of per hit).

__global__ __launch_bounds__(256) void k_scan_targets(
        const int4* __restrict__ esrc4, const int4* __restrict__ edst4,
        const int* __restrict__ flagL2, int* __restrict__ flagL1,
        int* __restrict__ deg2i, int* __restrict__ e2dst,
        int* __restrict__ e2src, int* __restrict__ cnt) {
    int t = blockIdx.x * blockDim.x + threadIdx.x;
    int lane = threadIdx.x & 63;
    int f[4] = {0, 0, 0, 0};
    int s[4];
    if (t < NE / 4) {
        int4 d4 = edst4[t];
        int4 s4 = esrc4[t];
        f[0] = flagL2[d4.x]; f[1] = flagL2[d4.y];
        f[2] = flagL2[d4.z]; f[3] = flagL2[d4.w];
        s[0] = s4.x; s[1] = s4.y; s[2] = s4.z; s[3] = s4.w;
    }
    int c = (f[0] > 0) + (f[1] > 0) + (f[2] > 0) + (f[3] > 0);
    int scan = c;
#pragma unroll
    for (int off = 1; off < 64; off <<= 1) {
        int n = __shfl_up(scan, off, 64);
        if (lane >= off) scan += n;
    }
    int total = __shfl(scan, 63, 64);
    int base = 0;
    if (lane == 63 && total) base = atomicAdd(&cnt[2], total);
    base = __shfl(base, 63, 64);
    int idx = base + scan - c;
#pragma unroll
    for (int j = 0; j < 4; ++j) {
        if (f[j] > 0) {
            if (idx < E2CAP) { e2dst[idx] = f[j] - 1; e2src[idx] = s[j]; }
            atomicAdd(&deg2i[f[j] - 1], 1);
            flagL1[s[j]] = 1;       // idempotent mark
            ++idx;
        }
    }
}

__global__ __launch_bounds__(256) void k_assign(
        int* __restrict__ flagL1, int* __restrict__ nodeL1, int* __restrict__ cnt) {
    int n = blockIdx.x * blockDim.x + threadIdx.x;
    bool pred = (n < NN) && (flagL1[n] != 0);
    unsigned long long mask = __ballot(pred);
    if (mask == 0) return;
    int lane = threadIdx.x & 63;
    int prefix = __popcll(mask & ((1ull << lane) - 1));
    int fl = __ffsll((long long)mask) - 1;
    int base = 0;
    if (lane == fl) base = atomicAdd(&cnt[0], __popcll(mask));
    base = __shfl(base, fl, 64);
    if (pred) {
        int slot = base + prefix;
        if (slot < L1CAP) { flagL1[n] = slot + 1; nodeL1[slot] = n; }
        else flagL1[n] = 0;     // overflow safety (never hit with this graph)
    }
}

__global__ __launch_bounds__(256) void k_scan_l1(
        const int4* __restrict__ esrc4, const int4* __restrict__ edst4,
        const int* __restrict__ flagL1, int* __restrict__ deg1i,
        int* __restrict__ e1dst, int* __restrict__ e1src, int* __restrict__ cnt) {
    int t = blockIdx.x * blockDim.x + threadIdx.x;
    int lane = threadIdx.x & 63;
    int f[4] = {0, 0, 0, 0};
    int s[4];
    if (t < NE / 4) {
        int4 d4 = edst4[t];
        int4 s4 = esrc4[t];
        f[0] = flagL1[d4.x]; f[1] = flagL1[d4.y];
        f[2] = flagL1[d4.z]; f[3] = flagL1[d4.w];
        s[0] = s4.x; s[1] = s4.y; s[2] = s4.z; s[3] = s4.w;
    }
    int c = (f[0] > 0) + (f[1] > 0) + (f[2] > 0) + (f[3] > 0);
    int scan = c;
#pragma unroll
    for (int off = 1; off < 64; off <<= 1) {
        int n = __shfl_up(scan, off, 64);
        if (lane >= off) scan += n;
    }
    int total = __shfl(scan, 63, 64);
    int base = 0;
    if (lane == 63 && total) base = atomicAdd(&cnt[1], total);
    base = __shfl(base, 63, 64);
    int idx = base + scan - c;
#pragma unroll
    for (int j = 0; j < 4; ++j) {
        if (f[j] > 0) {
            if (idx < E1CAP) { e1dst[idx] = f[j] - 1; e1src[idx] = s[j]; }
            atomicAdd(&deg1i[f[j] - 1], 1);
            ++idx;
        }
    }
}

__global__ void k_selfrow2(const int* __restrict__ nodeL2, const int* __restrict__ flagL1,
                           int* __restrict__ selfRow2) {
    int s = threadIdx.x;
    if (s < 257) selfRow2[s] = flagL1[nodeL2[s]] - 1;
    else if (s < L2CAP) selfRow2[s] = 0;
}

// ---------------- counting-sort by destination slot ----------------
// Exclusive prefix over per-slot degrees. block 0 -> layer-1 arrays,
// block 1 -> layer-2 arrays. 256 threads, chunked wave-scan.

__global__ __launch_bounds__(256) void k_prefix(
        const int* __restrict__ deg1, int* __restrict__ off1, int* __restrict__ cur1,
        const int* __restrict__ deg2, int* __restrict__ off2, int* __restrict__ cur2) {
    const int* deg; int* off; int* cur; int n;
    if (blockIdx.x == 0) { deg = deg1; off = off1; cur = cur1; n = L1CAP; }
    else                 { deg = deg2; off = off2; cur = cur2; n = L2CAP; }
    __shared__ int wsum[4];
    __shared__ int carry;
    int tid = threadIdx.x, lane = tid & 63, w = tid >> 6;
    if (tid == 0) carry = 0;
    __syncthreads();
    for (int base = 0; base < n; base += 256) {
        int i = base + tid;
        int v = (i < n) ? deg[i] : 0;
        int scan = v;
#pragma unroll
        for (int o = 1; o < 64; o <<= 1) {
            int t = __shfl_up(scan, o, 64);
            if (lane >= o) scan += t;
        }
        if (lane == 63) wsum[w] = scan;
        __syncthreads();
        int woff = 0;
        for (int k = 0; k < w; ++k) woff += wsum[k];
        int excl = carry + woff + scan - v;
        if (i < n) { off[i] = excl; cur[i] = excl; }
        __syncthreads();
        if (tid == 255) carry += wsum[0] + wsum[1] + wsum[2] + wsum[3];
        // next iteration's wsum write is by lane-63 threads after this barrier;
        // all reads of old wsum completed before it.
    }
}

// Scatter compact edge list into per-slot contiguous ranges. Atomics spread
// over ~4.4K cursor addresses (vs 1 before) — cheap. srcMap folds the
// h1c-row remap for layer 2.
__global__ __launch_bounds__(256) void k_bucket(
        const int* __restrict__ edst, const int* __restrict__ esrc,
        const int* __restrict__ cntPtr, int cap, const int* __restrict__ srcMap,
        int* __restrict__ cursor, int* __restrict__ bsrc) {
    int cnt = *cntPtr; if (cnt > cap) cnt = cap;
    int i = blockIdx.x * blockDim.x + threadIdx.x;
    if (i >= cnt) return;
    int d = edst[i], s = esrc[i];
    int row = srcMap ? (srcMap[s] - 1) : s;
    int pos = atomicAdd(&cursor[d], 1);
    bsrc[pos] = row;
}

// ---------------- aggregation gather (1 wave per slot, zero atomics) --------
// Previous push-scatter: 16.8M float atomics write-through to HBM = 67 MB
// WRITE_SIZE, 63 us. Pull: registers accumulate, one 512B store per slot.

__global__ __launch_bounds__(256) void k_gather(
        const int* __restrict__ off, const int* __restrict__ deg,
        const int* __restrict__ bsrc, const int* __restrict__ cntPtr,
        const float* __restrict__ srcMat, float* __restrict__ aggc) {
    int w = (blockIdx.x * blockDim.x + threadIdx.x) >> 6;
    int lane = threadIdx.x & 63;
    int cnt = *cntPtr;
    if (w >= cnt) return;
    int e0 = off[w], n = deg[w];
    float ax = 0.0f, ay = 0.0f;
    int e = e0;
    for (; e + 1 < e0 + n; e += 2) {       // 2-edge unroll for load ILP
        int r0 = bsrc[e], r1 = bsrc[e + 1];
        float2 v0 = ((const float2*)(srcMat + (size_t)r0 * FD))[lane];
        float2 v1 = ((const float2*)(srcMat + (size_t)r1 * FD))[lane];
        ax += v0.x + v1.x; ay += v0.y + v1.y;
    }
    if (e < e0 + n) {
        int r = bsrc[e];
        float2 v = ((const float2*)(srcMat + (size_t)r * FD))[lane];
        ax += v.x; ay += v.y;
    }
    float2 outv = {ax, ay};
    ((float2*)(aggc + (size_t)w * FD))[lane] = outv;
}

// ---------------- fused SAGE layer GEMM ----------------
// out[slot][o] = relu( self[slot]·Wself[o][:] + (agg[slot]/max(deg,1))·Wneigh[o][:] + b[o] )
// block = 128 thr, tile 32 slots x 128 outs, micro 4 slots x 8 outs.
// LDS row stride 132 -> sgroup broadcast reads hit banks {0,4,...,28}: conflict-free.

#define GSLOTS 32
#define LDSTR 132

__global__ __launch_bounds__(128) void k_gemm(
        const float* __restrict__ selfMat, const int* __restrict__ selfIdx,
        const float* __restrict__ aggc, const int* __restrict__ degc,
        const float* __restrict__ Wself, const float* __restrict__ Wneigh,
        const float* __restrict__ bias, float* __restrict__ outc,
        const int* __restrict__ cntPtr) {
    __shared__ float sx[GSLOTS][LDSTR];
    __shared__ float sa[GSLOTS][LDSTR];
    int cnt = *cntPtr;
    int base = blockIdx.x * GSLOTS;
    if (base >= cnt) return;
    int tid = threadIdx.x;

    for (int s = 0; s < GSLOTS; ++s) {
        int slot = base + s;
        int idx = (slot < cnt) ? selfIdx[slot] : 0;
        float inv = 1.0f / fmaxf((float)degc[slot], 1.0f);
        sx[s][tid] = selfMat[(size_t)idx * FD + tid];
        sa[s][tid] = aggc[(size_t)slot * FD + tid] * inv;
    }
    __syncthreads();

    int og = tid & 15;       // 16 out-groups -> o = og + 16*j
    int sg = tid >> 4;       // 8 slot-groups -> s = sg + 8*i
    float acc[4][8];
#pragma unroll
    for (int i = 0; i < 4; ++i)
#pragma unroll
        for (int j = 0; j < 8; ++j) acc[i][j] = 0.0f;

    for (int k = 0; k < FD; k += 4) {
        float4 xv[4], av[4];
#pragma unroll
        for (int i = 0; i < 4; ++i) {
            int s = sg + 8 * i;
            xv[i] = *(const float4*)&sx[s][k];
            av[i] = *(const float4*)&sa[s][k];
        }
#pragma unroll
        for (int j = 0; j < 8; ++j) {
            int o = og + 16 * j;
            float4 ws = *(const float4*)&Wself[(size_t)o * FD + k];
            float4 wn = *(const float4*)&Wneigh[(size_t)o * FD + k];
#pragma unroll
            for (int i = 0; i < 4; ++i) {
                acc[i][j] += xv[i].x * ws.x + xv[i].y * ws.y + xv[i].z * ws.z + xv[i].w * ws.w
                           + av[i].x * wn.x + av[i].y * wn.y + av[i].z * wn.z + av[i].w * wn.w;
            }
        }
    }

#pragma unroll
    for (int j = 0; j < 8; ++j) {
        int o = og + 16 * j;
        float b = bias[o];
#pragma unroll
        for (int i = 0; i < 4; ++i) {
            int slot = base + sg + 8 * i;
            outc[(size_t)slot * FD + o] = fmaxf(acc[i][j] + b, 0.0f);
        }
    }
}

// ---------------- readout ----------------
// Transposed: thread owns one feature, register fmax chain, zero atomics.

__global__ __launch_bounds__(256) void k_readout(
        const float* __restrict__ h2c, const int* __restrict__ flagL2,
        const int* __restrict__ states, const int* __restrict__ actions,
        const float* __restrict__ Wfc, const float* __restrict__ bfc,
        float* __restrict__ out) {
    __shared__ int slotS[256];
    __shared__ float halfmax[2][FD];
    __shared__ float red[256];
    int tid = threadIdx.x;
    slotS[tid] = flagL2[states[tid]] - 1;
    __syncthreads();

    int f = tid & (FD - 1);
    int half = tid >> 7;             // 0 or 1
    float m = 0.0f;                  // h2 >= 0 post-ReLU, 0 is identity for max
#pragma unroll 8
    for (int s = half * 128; s < half * 128 + 128; ++s) {
        m = fmaxf(m, h2c[(size_t)slotS[s] * FD + f]);
    }
    halfmax[half][f] = m;
    __syncthreads();

    float v = 0.0f;
    if (tid < FD) {
        int aslot = flagL2[actions[0]] - 1;
        float mm = fmaxf(halfmax[0][tid], halfmax[1][tid]);
        float av = h2c[(size_t)aslot * FD + tid];
        v = mm * Wfc[tid] + av * Wfc[FD + tid];
    }
    red[tid] = v;
    __syncthreads();
    for (int s = 128; s > 0; s >>= 1) {
        if (tid < s) red[tid] += red[tid + s];
        __syncthreads();
    }
    if (tid == 0) out[0] = red[0] + bfc[0];
}

// ---------------- launch ----------------

extern "C" void kernel_launch(void* const* d_in, const int* in_sizes, int n_in,
                              void* d_out, int out_size, void* d_ws, size_t ws_size,
                              hipStream_t stream) {
    const float* x    = (const float*)d_in[0];
    const int* esrc   = (const int*)d_in[1];
    const int* edst   = (const int*)d_in[2];
    const int* states = (const int*)d_in[3];
    const int* acts   = (const int*)d_in[4];
    const float* W1s  = (const float*)d_in[5];
    const float* W1n  = (const float*)d_in[6];
    const float* b1   = (const float*)d_in[7];
    const float* W2s  = (const float*)d_in[8];
    const float* W2n  = (const float*)d_in[9];
    const float* b2   = (const float*)d_in[10];
    const float* Wfc  = (const float*)d_in[11];
    const float* bfc  = (const float*)d_in[12];
    float* out = (float*)d_out;

    char* ws = (char*)d_ws;
    size_t o = 0;
    // --- zeroed region (single contiguous memset; agg/h no longer zeroed) ---
    size_t off_cnt    = o; o += 256;
    size_t off_flagL2 = o; o += ((size_t)NN * 4 + 255) / 256 * 256;
    size_t off_flagL1 = o; o += ((size_t)NN * 4 + 255) / 256 * 256;
    size_t off_deg1i  = o; o += ((size_t)L1CAP * 4 + 255) / 256 * 256;
    size_t off_deg2i  = o; o += (size_t)L2CAP * 4;
    size_t zero_bytes = o;                                      // ~0.6 MB
    // --- non-zeroed ---
    size_t off_nodeL2 = o; o += (size_t)L2CAP * 4;
    size_t off_selfR2 = o; o += (size_t)L2CAP * 4;
    size_t off_nodeL1 = o; o += ((size_t)L1CAP * 4 + 255) / 256 * 256;
    size_t off_e1dst  = o; o += (size_t)E1CAP * 4;
    size_t off_e1src  = o; o += (size_t)E1CAP * 4;
    size_t off_e2dst  = o; o += (size_t)E2CAP * 4;
    size_t off_e2src  = o; o += (size_t)E2CAP * 4;
    size_t off_off1   = o; o += (size_t)L1CAP * 4;
    size_t off_cur1   = o; o += (size_t)L1CAP * 4;
    size_t off_bsrc1  = o; o += (size_t)E1CAP * 4;
    size_t off_off2   = o; o += (size_t)L2CAP * 4;
    size_t off_cur2   = o; o += (size_t)L2CAP * 4;
    size_t off_bsrc2  = o; o += (size_t)E2CAP * 4;
    size_t off_agg1c  = o; o += (size_t)L1CAP * FD * 4;
    size_t off_agg2c  = o; o += (size_t)L2CAP * FD * 4;
    size_t off_h1c    = o; o += (size_t)L1CAP * FD * 4;
    size_t off_h2c    = o; o += (size_t)L2CAP * FD * 4;

    int*   cnt    = (int*)(ws + off_cnt);       // [0]=L1 slots [1]=E1 [2]=E2 [3]=L2 slots
    int*   flagL2 = (int*)(ws + off_flagL2);
    int*   flagL1 = (int*)(ws + off_flagL1);
    int*   deg1i  = (int*)(ws + off_deg1i);
    int*   deg2i  = (int*)(ws + off_deg2i);
    int*   nodeL2 = (int*)(ws + off_nodeL2);
    int*   selfR2 = (int*)(ws + off_selfR2);
    int*   nodeL1 = (int*)(ws + off_nodeL1);
    int*   e1dst  = (int*)(ws + off_e1dst);
    int*   e1src  = (int*)(ws + off_e1src);
    int*   e2dst  = (int*)(ws + off_e2dst);
    int*   e2src  = (int*)(ws + off_e2src);
    int*   off1   = (int*)(ws + off_off1);
    int*   cur1   = (int*)(ws + off_cur1);
    int*   bsrc1  = (int*)(ws + off_bsrc1);
    int*   off2   = (int*)(ws + off_off2);
    int*   cur2   = (int*)(ws + off_cur2);
    int*   bsrc2  = (int*)(ws + off_bsrc2);
    float* agg1c  = (float*)(ws + off_agg1c);
    float* agg2c  = (float*)(ws + off_agg2c);
    float* h1c    = (float*)(ws + off_h1c);
    float* h2c    = (float*)(ws + off_h2c);

    hipMemsetAsync(ws, 0, zero_bytes, stream);

    k_mark<<<1, 320, 0, stream>>>(states, acts, flagL2, flagL1, nodeL2, cnt);
    k_scan_targets<<<(NE / 4 + 255) / 256, 256, 0, stream>>>(
        (const int4*)esrc, (const int4*)edst, flagL2, flagL1, deg2i, e2dst, e2src, cnt);
    k_assign<<<(NN + 255) / 256, 256, 0, stream>>>(flagL1, nodeL1, cnt);
    k_scan_l1<<<(NE / 4 + 255) / 256, 256, 0, stream>>>(
        (const int4*)esrc, (const int4*)edst, flagL1, deg1i, e1dst, e1src, cnt);
    k_selfrow2<<<1, 512, 0, stream>>>(nodeL2, flagL1, selfR2);

    k_prefix<<<2, 256, 0, stream>>>(deg1i, off1, cur1, deg2i, off2, cur2);
    k_bucket<<<E1CAP / 256, 256, 0, stream>>>(e1dst, e1src, cnt + 1, E1CAP,
                                              nullptr, cur1, bsrc1);
    k_bucket<<<E2CAP / 256, 256, 0, stream>>>(e2dst, e2src, cnt + 2, E2CAP,
                                              flagL1, cur2, bsrc2);

    // layer 1: gather x over bucketed E1, fused GEMM -> h1c
    k_gather<<<L1CAP / 4, 256, 0, stream>>>(off1, deg1i, bsrc1, cnt + 0, x, agg1c);
    k_gemm<<<L1CAP / GSLOTS, 128, 0, stream>>>(x, nodeL1, agg1c, deg1i, W1s, W1n, b1,
                                               h1c, cnt + 0);
    // layer 2: gather h1 over bucketed E2, fused GEMM -> h2c
    k_gather<<<L2CAP / 4, 256, 0, stream>>>(off2, deg2i, bsrc2, cnt + 3, h1c, agg2c);
    k_gemm<<<L2CAP / GSLOTS, 128, 0, stream>>>(h1c, selfR2, agg2c, deg2i, W2s, W2n, b2,
                                               h2c, cnt + 3);

    k_readout<<<1, 256, 0, stream>>>(h2c, flagL2, states, acts, Wfc, bfc, out);
}